// Round 21
// baseline (155.677 us; speedup 1.0000x reference)
//
#include <hip/hip_runtime.h>
#include <hip/hip_bf16.h>

#define B_  4
#define C_  256
#define CB_ 32
#define N_  4096
#define LOG2E 1.4426950408889634f

typedef short bf16x8 __attribute__((ext_vector_type(8)));
typedef int   i32x2  __attribute__((ext_vector_type(2)));
typedef float f32x4  __attribute__((ext_vector_type(4)));
typedef float f32x16 __attribute__((ext_vector_type(16)));

static __device__ __forceinline__ bf16x8 ld_bf8(const __hip_bfloat16* p) {
    return *reinterpret_cast<const bf16x8*>(p);
}
// Truncating bf16 pair-pack: one v_perm_b32. Result = [hi16(a) | hi16(b)<<16].
static __device__ __forceinline__ unsigned pk2(float a, float b) {
    return __builtin_amdgcn_perm(__float_as_uint(a), __float_as_uint(b),
                                 0x03020706u);
}

// ---------------------------------------------------------------------------
// Workspace layout (all fragment-load-coalesced "k-major-8" forms):
//   Wc    bf16 [320][256]          @ 0x000000 (160 KiB)
//   q8    bf16 [B][4 dblk][N][8]   @ 0x040000 (1 MiB)   q PRE-SCALED by log2e
//   k8    bf16 [B][4 dblk][N][8]   @ 0x140000 (1 MiB)
//   rowE  fp32 [B][N]              @ 0x240000 (64 KiB)  e(m) = M'(m) + log2 Z(m)
//   pM    fp32 [4][B][N]           @ 0x250000 (256 KiB)
//   pZ    fp32 [4][B][N]           @ 0x290000 (256 KiB)
//   v8    bf16 [B][N/8][C][8]      @ 0x400000 (8 MiB)
// All softmax math in exp2 domain: P = 2^(S' - e), S' = (q*log2e).k.
// ---------------------------------------------------------------------------

__global__ __launch_bounds__(256) void wconv(
    const float* __restrict__ Wq, const float* __restrict__ Wk,
    const float* __restrict__ Wv, __hip_bfloat16* __restrict__ Wc)
{
    int idx = (blockIdx.x * 256 + threadIdx.x) * 4;
    if (idx >= 320 * 256) return;
    int o = idx >> 8, c = idx & 255;
    const float* src = o < 32 ? Wq + o * 256 + c
                     : o < 64 ? Wk + (o - 32) * 256 + c
                              : Wv + (o - 64) * 256 + c;
    float4 f = *reinterpret_cast<const float4*>(src);
    union { __hip_bfloat16 h[4]; uint2 u; } pk;
    pk.h[0] = __float2bfloat16(f.x); pk.h[1] = __float2bfloat16(f.y);
    pk.h[2] = __float2bfloat16(f.z); pk.h[3] = __float2bfloat16(f.w);
    *reinterpret_cast<uint2*>(Wc + idx) = pk.u;
}

// Fused QKV projection, MFMA 16x16x32. Block: 64 n, all 320 output rows,
// single barrier (full 256c x 64n x-tile staged to LDS transposed).
// q rows scaled by log2e on store (exp2-domain softmax downstream).
__global__ __launch_bounds__(256) void qkv_gemm(
    const float* __restrict__ x, const __hip_bfloat16* __restrict__ Wc,
    const float* __restrict__ bq, const float* __restrict__ bk,
    const float* __restrict__ bv,
    __hip_bfloat16* __restrict__ q8, __hip_bfloat16* __restrict__ k8,
    __hip_bfloat16* __restrict__ v8)
{
    const int b = blockIdx.y, n0 = blockIdx.x * 64;
    const int tid = threadIdx.x, lane = tid & 63, w = tid >> 6;
    const int lg = lane >> 4, lr = lane & 15;
    __shared__ __attribute__((aligned(16))) __hip_bfloat16 T[64][264]; // [n][c]
    const float* xb = x + (size_t)b * C_ * N_;

    {
        const int hi = tid >> 4, n4 = (tid & 15) * 4;
#pragma unroll
        for (int i = 0; i < 16; ++i) {
            const int c = i * 16 + hi;
            float4 f = *reinterpret_cast<const float4*>(
                &xb[(size_t)c * N_ + n0 + n4]);
            T[n4 + 0][c] = __float2bfloat16(f.x);
            T[n4 + 1][c] = __float2bfloat16(f.y);
            T[n4 + 2][c] = __float2bfloat16(f.z);
            T[n4 + 3][c] = __float2bfloat16(f.w);
        }
    }
    __syncthreads();

    f32x4 acc[5][4] = {};
#pragma unroll
    for (int s = 0; s < 8; ++s) {
        const int c0 = s * 32;
        bf16x8 bfr[4];
#pragma unroll
        for (int nf = 0; nf < 4; ++nf)
            bfr[nf] = *reinterpret_cast<const bf16x8*>(&T[nf * 16 + lr][c0 + lg * 8]);
#pragma unroll
        for (int t = 0; t < 5; ++t) {
            const int of = w + 4 * t;
            bf16x8 af = ld_bf8(Wc + (size_t)(of * 16 + lr) * 256 + c0 + lg * 8);
#pragma unroll
            for (int nf = 0; nf < 4; ++nf)
                acc[t][nf] = __builtin_amdgcn_mfma_f32_16x16x32_bf16(af, bfr[nf], acc[t][nf], 0, 0, 0);
        }
    }
#pragma unroll
    for (int t = 0; t < 5; ++t) {
        const int of = w + 4 * t, ob = of * 16 + lg * 4;
        float bias[4];
#pragma unroll
        for (int i = 0; i < 4; ++i) {
            int o = ob + i;
            bias[i] = o < 32 ? bq[o] : o < 64 ? bk[o - 32] : bv[o - 64];
        }
#pragma unroll
        for (int nf = 0; nf < 4; ++nf) {
            const int n = n0 + nf * 16 + lr;
            if (ob < 32) {          // q: scale into exp2 domain
                union { __hip_bfloat16 h[4]; uint2 u; } pk;
#pragma unroll
                for (int i = 0; i < 4; ++i)
                    pk.h[i] = __float2bfloat16((acc[t][nf][i] + bias[i]) * LOG2E);
                *reinterpret_cast<uint2*>(
                    q8 + ((size_t)(b * 4 + (ob >> 3)) * N_ + n) * 8 + (ob & 7)) = pk.u;
            } else if (ob < 64) {   // k
                union { __hip_bfloat16 h[4]; uint2 u; } pk;
#pragma unroll
                for (int i = 0; i < 4; ++i)
                    pk.h[i] = __float2bfloat16(acc[t][nf][i] + bias[i]);
                const int ok = ob - 32;
                *reinterpret_cast<uint2*>(
                    k8 + ((size_t)(b * 4 + (ok >> 3)) * N_ + n) * 8 + (ok & 7)) = pk.u;
            } else {    // v -> [b][n/8][C][8]
#pragma unroll
                for (int i = 0; i < 4; ++i)
                    v8[((size_t)(b * (N_ / 8) + (n >> 3)) * C_ + (ob - 64 + i)) * 8
                       + (n & 7)] = __float2bfloat16(acc[t][nf][i] + bias[i]);
            }
        }
    }
}

// Partial row stats over an n-quarter (16x16x32 MFMA), exp2 domain.
__global__ __launch_bounds__(256) void row_stats_part(
    const __hip_bfloat16* __restrict__ q8, const __hip_bfloat16* __restrict__ k8,
    float* __restrict__ pM, float* __restrict__ pZ)
{
    const int m0 = blockIdx.x * 64, s = blockIdx.y, b = blockIdx.z;
    const int tid = threadIdx.x, lane = tid & 63, w = tid >> 6;
    const int lg = lane >> 4, lr = lane & 15;
    const __hip_bfloat16* q8b = q8 + (size_t)b * N_ * CB_;
    const __hip_bfloat16* k8b = k8 + (size_t)b * N_ * CB_;
    const int mrow = m0 + w * 16;
    bf16x8 qf = ld_bf8(q8b + ((size_t)lg * N_ + mrow + lr) * 8);
    float rm[4] = {-1e30f, -1e30f, -1e30f, -1e30f};
    float rz[4] = {0.f, 0.f, 0.f, 0.f};
    const f32x4 zero = {0.f, 0.f, 0.f, 0.f};
    const int nbeg = s * (N_ / 4);
    for (int n = nbeg; n < nbeg + N_ / 4; n += 64) {
        f32x4 sf[4];
#pragma unroll
        for (int nf = 0; nf < 4; ++nf) {
            bf16x8 kf = ld_bf8(k8b + ((size_t)lg * N_ + n + nf * 16 + lr) * 8);
            sf[nf] = __builtin_amdgcn_mfma_f32_16x16x32_bf16(qf, kf, zero, 0, 0, 0);
        }
#pragma unroll
        for (int i = 0; i < 4; ++i) {
            float tm = fmaxf(fmaxf(sf[0][i], sf[1][i]), fmaxf(sf[2][i], sf[3][i]));
            if (tm > rm[i]) { rz[i] *= exp2f(rm[i] - tm); rm[i] = tm; }
            rz[i] += exp2f(sf[0][i] - rm[i]) + exp2f(sf[1][i] - rm[i]) +
                     exp2f(sf[2][i] - rm[i]) + exp2f(sf[3][i] - rm[i]);
        }
    }
#pragma unroll
    for (int off = 1; off < 16; off <<= 1) {
#pragma unroll
        for (int i = 0; i < 4; ++i) {
            float om = __shfl_xor(rm[i], off);
            float oz = __shfl_xor(rz[i], off);
            float nm = fmaxf(rm[i], om);
            rz[i] = rz[i] * exp2f(rm[i] - nm) + oz * exp2f(om - nm);
            rm[i] = nm;
        }
    }
    if (lr == 0) {
        const size_t base = ((size_t)s * B_ + b) * N_ + mrow + lg * 4;
#pragma unroll
        for (int i = 0; i < 4; ++i) { pM[base + i] = rm[i]; pZ[base + i] = rz[i]; }
    }
}

__global__ __launch_bounds__(256) void stats_combine(
    const float* __restrict__ pM, const float* __restrict__ pZ,
    float* __restrict__ rowE)
{
    const int i = blockIdx.x * 256 + threadIdx.x;   // over B_*N_
    const int BN = B_ * N_;
    float m0 = pM[i], m1 = pM[BN + i], m2 = pM[2 * BN + i], m3 = pM[3 * BN + i];
    float M = fmaxf(fmaxf(m0, m1), fmaxf(m2, m3));
    float Z = pZ[i]          * exp2f(m0 - M) + pZ[BN + i]     * exp2f(m1 - M)
            + pZ[2 * BN + i] * exp2f(m2 - M) + pZ[3 * BN + i] * exp2f(m3 - M);
    rowE[i] = M + log2f(Z);
}

// out[c,n] = x[c,n] + sum_m v[c,m] * 2^(S'(m,n) - e(m)).
// Block: 128c x 64n, 8 waves = 4 m-splits (ms) x 2 n-halves (nf). Grid 512,
// XCD swizzle. Pipeline: S[i], PV[i-1], loads[i+1], exp2/pack[i]. R17 body +
// exp2 (saves 16 v_mul/body) + s_setprio(1) around the MFMA cluster (T5:
// barrier-free waves = attn-like regime, +4-7% in m191).
#define PIPE_BODY(qC0, qC1, vP, eC, qN0, qN1, vN, eN, qpN0, qpN1, vpN0, vpN1, epN, DO_LOAD) \
  {                                                                             \
    __builtin_amdgcn_s_setprio(1);                                              \
    f32x16 sf = {};                                                             \
    sf = __builtin_amdgcn_mfma_f32_32x32x16_bf16(qC0, kB0, sf, 0, 0, 0);        \
    sf = __builtin_amdgcn_mfma_f32_32x32x16_bf16(qC1, kB1, sf, 0, 0, 0);        \
    _Pragma("unroll")                                                           \
    for (int ct = 0; ct < 4; ++ct) {                                            \
      acc[ct] = __builtin_amdgcn_mfma_f32_32x32x16_bf16(vP[ct][0], pf0, acc[ct], 0, 0, 0); \
      acc[ct] = __builtin_amdgcn_mfma_f32_32x32x16_bf16(vP[ct][1], pf1, acc[ct], 0, 0, 0); \
    }                                                                           \
    __builtin_amdgcn_s_setprio(0);                                              \
    if (DO_LOAD) {                                                              \
      qN0 = ld_bf8(qpN0); qN1 = ld_bf8(qpN1);                                   \
      _Pragma("unroll")                                                         \
      for (int ct = 0; ct < 4; ++ct) {                                          \
        vN[ct][0] = ld_bf8(vpN0 + ct * 256);                                    \
        vN[ct][1] = ld_bf8(vpN1 + ct * 256);                                    \
      }                                                                         \
      _Pragma("unroll")                                                         \
      for (int g = 0; g < 4; ++g)                                               \
        eN[g] = *reinterpret_cast<const f32x4*>(epN + 8 * g);                   \
      qpN0 += 2048; qpN1 += 2048; vpN0 += 65536; vpN1 += 65536; epN += 256;     \
    }                                                                           \
    unsigned W0 = pk2(exp2f(sf[0]  - eC[0][0]), exp2f(sf[1]  - eC[0][1]));      \
    unsigned W1 = pk2(exp2f(sf[2]  - eC[0][2]), exp2f(sf[3]  - eC[0][3]));      \
    unsigned W2 = pk2(exp2f(sf[4]  - eC[1][0]), exp2f(sf[5]  - eC[1][1]));      \
    unsigned W3 = pk2(exp2f(sf[6]  - eC[1][2]), exp2f(sf[7]  - eC[1][3]));      \
    unsigned W4 = pk2(exp2f(sf[8]  - eC[2][0]), exp2f(sf[9]  - eC[2][1]));      \
    unsigned W5 = pk2(exp2f(sf[10] - eC[2][2]), exp2f(sf[11] - eC[2][3]));      \
    unsigned W6 = pk2(exp2f(sf[12] - eC[3][0]), exp2f(sf[13] - eC[3][1]));      \
    unsigned W7 = pk2(exp2f(sf[14] - eC[3][2]), exp2f(sf[15] - eC[3][3]));      \
    i32x2 s02 = __builtin_amdgcn_permlane32_swap((int)W0, (int)W2, false, false);\
    i32x2 s13 = __builtin_amdgcn_permlane32_swap((int)W1, (int)W3, false, false);\
    i32x2 s46 = __builtin_amdgcn_permlane32_swap((int)W4, (int)W6, false, false);\
    i32x2 s57 = __builtin_amdgcn_permlane32_swap((int)W5, (int)W7, false, false);\
    union { int u[4]; bf16x8 v8_; } f0, f1;                                     \
    f0.u[0] = s02[0]; f0.u[1] = s13[0]; f0.u[2] = s02[1]; f0.u[3] = s13[1];     \
    f1.u[0] = s46[0]; f1.u[1] = s57[0]; f1.u[2] = s46[1]; f1.u[3] = s57[1];     \
    pf0 = f0.v8_; pf1 = f1.v8_;                                                 \
  }

__global__ __launch_bounds__(512) void pv_attn(
    const __hip_bfloat16* __restrict__ q8, const __hip_bfloat16* __restrict__ k8,
    const __hip_bfloat16* __restrict__ v8, const float* __restrict__ rowE,
    const float* __restrict__ x, float* __restrict__ out)
{
    const int bid = blockIdx.x;
    const int xcd = bid & 7, slot = bid >> 3;
    const int b = xcd >> 1, c0 = (xcd & 1) * 128, n0 = slot * 64;
    const int tid = threadIdx.x, lane = tid & 63, w = tid >> 6;
    const int ms = w >> 1, nf = w & 1;
    const int h = lane >> 5, l31 = lane & 31;
    const __hip_bfloat16* q8b = q8 + (size_t)b * N_ * CB_;
    const __hip_bfloat16* k8b = k8 + (size_t)b * N_ * CB_;
    const __hip_bfloat16* v8b = v8 + (size_t)b * (N_ / 8) * C_ * 8;

    // K B-frags for this wave's n-slice (loop-invariant)
    const int nrow = n0 + nf * 32 + l31;
    bf16x8 kB0 = ld_bf8(k8b + ((size_t)h * N_ + nrow) * 8);
    bf16x8 kB1 = ld_bf8(k8b + ((size_t)(2 + h) * N_ + nrow) * 8);

    // ping-pong pointers (A: even 128-m windows, B: odd)
    const __hip_bfloat16* qpA0 = q8b + ((size_t)h * N_ + ms * 32 + l31) * 8;
    const __hip_bfloat16* qpA1 = q8b + ((size_t)(2 + h) * N_ + ms * 32 + l31) * 8;
    const __hip_bfloat16* qpB0 = qpA0 + 128 * 8;
    const __hip_bfloat16* qpB1 = qpA1 + 128 * 8;
    const __hip_bfloat16* vpA0 = v8b + ((size_t)(ms * 4 + h) * C_ + c0 + l31) * 8;
    const __hip_bfloat16* vpA1 = v8b + ((size_t)(ms * 4 + 2 + h) * C_ + c0 + l31) * 8;
    const __hip_bfloat16* vpB0 = vpA0 + (size_t)16 * C_ * 8;
    const __hip_bfloat16* vpB1 = vpA1 + (size_t)16 * C_ * 8;
    const float* epA = rowE + (size_t)b * N_ + 4 * h + ms * 32;
    const float* epB = epA + 128;

    f32x16 acc[4] = {};
    bf16x8 qA0, qA1, qB0, qB1;
    bf16x8 vA[4][2], vB[4][2];
    f32x4 eA[4], eB[4];
    bf16x8 pf0, pf1;

    // prologue: load set A (window 0)
    qA0 = ld_bf8(qpA0); qA1 = ld_bf8(qpA1);
#pragma unroll
    for (int ct = 0; ct < 4; ++ct) {
        vA[ct][0] = ld_bf8(vpA0 + ct * 256);
        vA[ct][1] = ld_bf8(vpA1 + ct * 256);
    }
#pragma unroll
    for (int g = 0; g < 4; ++g)
        eA[g] = *reinterpret_cast<const f32x4*>(epA + 8 * g);
    qpA0 += 2048; qpA1 += 2048; vpA0 += 65536; vpA1 += 65536; epA += 256;

    // S[0] + exp2/pack -> pf (no PV yet)
    {
        f32x16 sf = {};
        sf = __builtin_amdgcn_mfma_f32_32x32x16_bf16(qA0, kB0, sf, 0, 0, 0);
        sf = __builtin_amdgcn_mfma_f32_32x32x16_bf16(qA1, kB1, sf, 0, 0, 0);
        unsigned W0 = pk2(exp2f(sf[0]  - eA[0][0]), exp2f(sf[1]  - eA[0][1]));
        unsigned W1 = pk2(exp2f(sf[2]  - eA[0][2]), exp2f(sf[3]  - eA[0][3]));
        unsigned W2 = pk2(exp2f(sf[4]  - eA[1][0]), exp2f(sf[5]  - eA[1][1]));
        unsigned W3 = pk2(exp2f(sf[6]  - eA[1][2]), exp2f(sf[7]  - eA[1][3]));
        unsigned W4 = pk2(exp2f(sf[8]  - eA[2][0]), exp2f(sf[9]  - eA[2][1]));
        unsigned W5 = pk2(exp2f(sf[10] - eA[2][2]), exp2f(sf[11] - eA[2][3]));
        unsigned W6 = pk2(exp2f(sf[12] - eA[3][0]), exp2f(sf[13] - eA[3][1]));
        unsigned W7 = pk2(exp2f(sf[14] - eA[3][2]), exp2f(sf[15] - eA[3][3]));
        i32x2 s02 = __builtin_amdgcn_permlane32_swap((int)W0, (int)W2, false, false);
        i32x2 s13 = __builtin_amdgcn_permlane32_swap((int)W1, (int)W3, false, false);
        i32x2 s46 = __builtin_amdgcn_permlane32_swap((int)W4, (int)W6, false, false);
        i32x2 s57 = __builtin_amdgcn_permlane32_swap((int)W5, (int)W7, false, false);
        union { int u[4]; bf16x8 v8_; } f0, f1;
        f0.u[0] = s02[0]; f0.u[1] = s13[0]; f0.u[2] = s02[1]; f0.u[3] = s13[1];
        f1.u[0] = s46[0]; f1.u[1] = s57[0]; f1.u[2] = s46[1]; f1.u[3] = s57[1];
        pf0 = f0.v8_; pf1 = f1.v8_;
    }
    // load set B (window 1)
    qB0 = ld_bf8(qpB0); qB1 = ld_bf8(qpB1);
#pragma unroll
    for (int ct = 0; ct < 4; ++ct) {
        vB[ct][0] = ld_bf8(vpB0 + ct * 256);
        vB[ct][1] = ld_bf8(vpB1 + ct * 256);
    }
#pragma unroll
    for (int g = 0; g < 4; ++g)
        eB[g] = *reinterpret_cast<const f32x4*>(epB + 8 * g);
    qpB0 += 2048; qpB1 += 2048; vpB0 += 65536; vpB1 += 65536; epB += 256;

    // pipelined bodies i=1..31 — rolled
#pragma unroll 1
    for (int it = 0; it < 15; ++it) {
        PIPE_BODY(qB0, qB1, vA, eB, qA0, qA1, vA, eA, qpA0, qpA1, vpA0, vpA1, epA, true)
        PIPE_BODY(qA0, qA1, vB, eA, qB0, qB1, vB, eB, qpB0, qpB1, vpB0, vpB1, epB, true)
    }
    PIPE_BODY(qB0, qB1, vA, eB, qA0, qA1, vA, eA, qpA0, qpA1, vpA0, vpA1, epA, false)
    // epilogue: PV[31] from set B
#pragma unroll
    for (int ct = 0; ct < 4; ++ct) {
        acc[ct] = __builtin_amdgcn_mfma_f32_32x32x16_bf16(vB[ct][0], pf0, acc[ct], 0, 0, 0);
        acc[ct] = __builtin_amdgcn_mfma_f32_32x32x16_bf16(vB[ct][1], pf1, acc[ct], 0, 0, 0);
    }

    // 4-phase ms-reduction through LDS (nf pair writes disjoint columns)
    __shared__ __attribute__((aligned(16))) float R[128][68];
#pragma unroll 1
    for (int p = 3; p >= 0; --p) {
        if (ms == p) {
#pragma unroll
            for (int i = 0; i < 16; ++i) {
                const int cl = (i & 3) + 8 * (i >> 2) + 4 * h;
                const int nn = nf * 32 + l31;
#pragma unroll
                for (int ct = 0; ct < 4; ++ct) {
                    if (p == 3) R[ct * 32 + cl][nn] = acc[ct][i];
                    else        R[ct * 32 + cl][nn] += acc[ct][i];
                }
            }
        }
        __syncthreads();
    }
    // epilogue: out = R + x (128 rows x 64 cols, 16 floats/thread)
    const int cr = tid >> 2, n16 = (tid & 3) * 16;
#pragma unroll
    for (int j = 0; j < 4; ++j) {
        f32x4 rv = *reinterpret_cast<const f32x4*>(&R[cr][n16 + 4 * j]);
        const size_t gi = ((size_t)b * C_ + c0 + cr) * N_ + n0 + n16 + 4 * j;
        f32x4 xv = *reinterpret_cast<const f32x4*>(x + gi);
        *reinterpret_cast<f32x4*>(out + gi) = rv + xv;
    }
}

extern "C" void kernel_launch(void* const* d_in, const int* in_sizes, int n_in,
                              void* d_out, int out_size, void* d_ws, size_t ws_size,
                              hipStream_t stream)
{
    const float* x  = (const float*)d_in[0];
    const float* Wq = (const float*)d_in[1];
    const float* bq = (const float*)d_in[2];
    const float* Wk = (const float*)d_in[3];
    const float* bk = (const float*)d_in[4];
    const float* Wv = (const float*)d_in[5];
    const float* bv = (const float*)d_in[6];
    float* out = (float*)d_out;

    char* ws = (char*)d_ws;
    __hip_bfloat16* Wc   = (__hip_bfloat16*)(ws);
    __hip_bfloat16* q8   = (__hip_bfloat16*)(ws + 0x040000);
    __hip_bfloat16* k8   = (__hip_bfloat16*)(ws + 0x140000);
    float*          rowE = (float*)(ws + 0x240000);
    float*          pM   = (float*)(ws + 0x250000);
    float*          pZ   = (float*)(ws + 0x290000);
    __hip_bfloat16* v8   = (__hip_bfloat16*)(ws + 0x400000);

    wconv<<<80, 256, 0, stream>>>(Wq, Wk, Wv, Wc);
    qkv_gemm<<<dim3(N_ / 64, B_), 256, 0, stream>>>(x, Wc, bq, bk, bv, q8, k8, v8);
    row_stats_part<<<dim3(N_ / 64, 4, B_), 256, 0, stream>>>(q8, k8, pM, pZ);
    stats_combine<<<B_ * N_ / 256, 256, 0, stream>>>(pM, pZ, rowE);
    pv_attn<<<512, 512, 0, stream>>>(q8, k8, v8, rowE, x, out);
}

// Round 22
// 133.188 us; speedup vs baseline: 1.1689x; 1.1689x over previous
//
#include <hip/hip_runtime.h>
#include <hip/hip_bf16.h>

#define B_  4
#define C_  256
#define CB_ 32
#define N_  4096
#define LOG2E 1.4426950408889634f

typedef short bf16x8 __attribute__((ext_vector_type(8)));
typedef int   i32x2  __attribute__((ext_vector_type(2)));
typedef float f32x4  __attribute__((ext_vector_type(4)));
typedef float f32x16 __attribute__((ext_vector_type(16)));

static __device__ __forceinline__ bf16x8 ld_bf8(const __hip_bfloat16* p) {
    return *reinterpret_cast<const bf16x8*>(p);
}
// Truncating bf16 pair-pack: one v_perm_b32. Result = [hi16(a) | hi16(b)<<16].
static __device__ __forceinline__ unsigned pk2(float a, float b) {
    return __builtin_amdgcn_perm(__float_as_uint(a), __float_as_uint(b),
                                 0x03020706u);
}
// Raw v_exp_f32 (2^x), 1 instruction — NOT the precise libm exp2f.
static __device__ __forceinline__ float ex2(float x) {
    return __builtin_amdgcn_exp2f(x);
}

// ---------------------------------------------------------------------------
// Workspace layout (all fragment-load-coalesced "k-major-8" forms):
//   Wc    bf16 [320][256]          @ 0x000000 (160 KiB)
//   q8    bf16 [B][4 dblk][N][8]   @ 0x040000 (1 MiB)   q PRE-SCALED by log2e
//   k8    bf16 [B][4 dblk][N][8]   @ 0x140000 (1 MiB)
//   rowE  fp32 [B][N]              @ 0x240000 (64 KiB)  e(m) = M'(m) + log2 Z(m)
//   pM    fp32 [4][B][N]           @ 0x250000 (256 KiB)
//   pZ    fp32 [4][B][N]           @ 0x290000 (256 KiB)
//   v8    bf16 [B][N/8][C][8]      @ 0x400000 (8 MiB)
// All softmax math in exp2 domain via raw v_exp_f32.
// ---------------------------------------------------------------------------

__global__ __launch_bounds__(256) void wconv(
    const float* __restrict__ Wq, const float* __restrict__ Wk,
    const float* __restrict__ Wv, __hip_bfloat16* __restrict__ Wc)
{
    int idx = (blockIdx.x * 256 + threadIdx.x) * 4;
    if (idx >= 320 * 256) return;
    int o = idx >> 8, c = idx & 255;
    const float* src = o < 32 ? Wq + o * 256 + c
                     : o < 64 ? Wk + (o - 32) * 256 + c
                              : Wv + (o - 64) * 256 + c;
    float4 f = *reinterpret_cast<const float4*>(src);
    union { __hip_bfloat16 h[4]; uint2 u; } pk;
    pk.h[0] = __float2bfloat16(f.x); pk.h[1] = __float2bfloat16(f.y);
    pk.h[2] = __float2bfloat16(f.z); pk.h[3] = __float2bfloat16(f.w);
    *reinterpret_cast<uint2*>(Wc + idx) = pk.u;
}

// Fused QKV projection, MFMA 16x16x32. Block: 64 n, all 320 output rows,
// single barrier. q rows scaled by log2e on store.
__global__ __launch_bounds__(256) void qkv_gemm(
    const float* __restrict__ x, const __hip_bfloat16* __restrict__ Wc,
    const float* __restrict__ bq, const float* __restrict__ bk,
    const float* __restrict__ bv,
    __hip_bfloat16* __restrict__ q8, __hip_bfloat16* __restrict__ k8,
    __hip_bfloat16* __restrict__ v8)
{
    const int b = blockIdx.y, n0 = blockIdx.x * 64;
    const int tid = threadIdx.x, lane = tid & 63, w = tid >> 6;
    const int lg = lane >> 4, lr = lane & 15;
    __shared__ __attribute__((aligned(16))) __hip_bfloat16 T[64][264]; // [n][c]
    const float* xb = x + (size_t)b * C_ * N_;

    {
        const int hi = tid >> 4, n4 = (tid & 15) * 4;
#pragma unroll
        for (int i = 0; i < 16; ++i) {
            const int c = i * 16 + hi;
            float4 f = *reinterpret_cast<const float4*>(
                &xb[(size_t)c * N_ + n0 + n4]);
            T[n4 + 0][c] = __float2bfloat16(f.x);
            T[n4 + 1][c] = __float2bfloat16(f.y);
            T[n4 + 2][c] = __float2bfloat16(f.z);
            T[n4 + 3][c] = __float2bfloat16(f.w);
        }
    }
    __syncthreads();

    f32x4 acc[5][4] = {};
#pragma unroll
    for (int s = 0; s < 8; ++s) {
        const int c0 = s * 32;
        bf16x8 bfr[4];
#pragma unroll
        for (int nf = 0; nf < 4; ++nf)
            bfr[nf] = *reinterpret_cast<const bf16x8*>(&T[nf * 16 + lr][c0 + lg * 8]);
#pragma unroll
        for (int t = 0; t < 5; ++t) {
            const int of = w + 4 * t;
            bf16x8 af = ld_bf8(Wc + (size_t)(of * 16 + lr) * 256 + c0 + lg * 8);
#pragma unroll
            for (int nf = 0; nf < 4; ++nf)
                acc[t][nf] = __builtin_amdgcn_mfma_f32_16x16x32_bf16(af, bfr[nf], acc[t][nf], 0, 0, 0);
        }
    }
#pragma unroll
    for (int t = 0; t < 5; ++t) {
        const int of = w + 4 * t, ob = of * 16 + lg * 4;
        float bias[4];
#pragma unroll
        for (int i = 0; i < 4; ++i) {
            int o = ob + i;
            bias[i] = o < 32 ? bq[o] : o < 64 ? bk[o - 32] : bv[o - 64];
        }
#pragma unroll
        for (int nf = 0; nf < 4; ++nf) {
            const int n = n0 + nf * 16 + lr;
            if (ob < 32) {          // q: scale into exp2 domain
                union { __hip_bfloat16 h[4]; uint2 u; } pk;
#pragma unroll
                for (int i = 0; i < 4; ++i)
                    pk.h[i] = __float2bfloat16((acc[t][nf][i] + bias[i]) * LOG2E);
                *reinterpret_cast<uint2*>(
                    q8 + ((size_t)(b * 4 + (ob >> 3)) * N_ + n) * 8 + (ob & 7)) = pk.u;
            } else if (ob < 64) {   // k
                union { __hip_bfloat16 h[4]; uint2 u; } pk;
#pragma unroll
                for (int i = 0; i < 4; ++i)
                    pk.h[i] = __float2bfloat16(acc[t][nf][i] + bias[i]);
                const int ok = ob - 32;
                *reinterpret_cast<uint2*>(
                    k8 + ((size_t)(b * 4 + (ok >> 3)) * N_ + n) * 8 + (ok & 7)) = pk.u;
            } else {    // v -> [b][n/8][C][8]
#pragma unroll
                for (int i = 0; i < 4; ++i)
                    v8[((size_t)(b * (N_ / 8) + (n >> 3)) * C_ + (ob - 64 + i)) * 8
                       + (n & 7)] = __float2bfloat16(acc[t][nf][i] + bias[i]);
            }
        }
    }
}

// Partial row stats over an n-quarter (16x16x32 MFMA), exp2 domain (raw v_exp).
__global__ __launch_bounds__(256) void row_stats_part(
    const __hip_bfloat16* __restrict__ q8, const __hip_bfloat16* __restrict__ k8,
    float* __restrict__ pM, float* __restrict__ pZ)
{
    const int m0 = blockIdx.x * 64, s = blockIdx.y, b = blockIdx.z;
    const int tid = threadIdx.x, lane = tid & 63, w = tid >> 6;
    const int lg = lane >> 4, lr = lane & 15;
    const __hip_bfloat16* q8b = q8 + (size_t)b * N_ * CB_;
    const __hip_bfloat16* k8b = k8 + (size_t)b * N_ * CB_;
    const int mrow = m0 + w * 16;
    bf16x8 qf = ld_bf8(q8b + ((size_t)lg * N_ + mrow + lr) * 8);
    float rm[4] = {-1e30f, -1e30f, -1e30f, -1e30f};
    float rz[4] = {0.f, 0.f, 0.f, 0.f};
    const f32x4 zero = {0.f, 0.f, 0.f, 0.f};
    const int nbeg = s * (N_ / 4);
    for (int n = nbeg; n < nbeg + N_ / 4; n += 64) {
        f32x4 sf[4];
#pragma unroll
        for (int nf = 0; nf < 4; ++nf) {
            bf16x8 kf = ld_bf8(k8b + ((size_t)lg * N_ + n + nf * 16 + lr) * 8);
            sf[nf] = __builtin_amdgcn_mfma_f32_16x16x32_bf16(qf, kf, zero, 0, 0, 0);
        }
#pragma unroll
        for (int i = 0; i < 4; ++i) {
            float tm = fmaxf(fmaxf(sf[0][i], sf[1][i]), fmaxf(sf[2][i], sf[3][i]));
            if (tm > rm[i]) { rz[i] *= ex2(rm[i] - tm); rm[i] = tm; }
            rz[i] += ex2(sf[0][i] - rm[i]) + ex2(sf[1][i] - rm[i]) +
                     ex2(sf[2][i] - rm[i]) + ex2(sf[3][i] - rm[i]);
        }
    }
#pragma unroll
    for (int off = 1; off < 16; off <<= 1) {
#pragma unroll
        for (int i = 0; i < 4; ++i) {
            float om = __shfl_xor(rm[i], off);
            float oz = __shfl_xor(rz[i], off);
            float nm = fmaxf(rm[i], om);
            rz[i] = rz[i] * ex2(rm[i] - nm) + oz * ex2(om - nm);
            rm[i] = nm;
        }
    }
    if (lr == 0) {
        const size_t base = ((size_t)s * B_ + b) * N_ + mrow + lg * 4;
#pragma unroll
        for (int i = 0; i < 4; ++i) { pM[base + i] = rm[i]; pZ[base + i] = rz[i]; }
    }
}

__global__ __launch_bounds__(256) void stats_combine(
    const float* __restrict__ pM, const float* __restrict__ pZ,
    float* __restrict__ rowE)
{
    const int i = blockIdx.x * 256 + threadIdx.x;   // over B_*N_
    const int BN = B_ * N_;
    float m0 = pM[i], m1 = pM[BN + i], m2 = pM[2 * BN + i], m3 = pM[3 * BN + i];
    float M = fmaxf(fmaxf(m0, m1), fmaxf(m2, m3));
    float Z = pZ[i]          * ex2(m0 - M) + pZ[BN + i]     * ex2(m1 - M)
            + pZ[2 * BN + i] * ex2(m2 - M) + pZ[3 * BN + i] * ex2(m3 - M);
    rowE[i] = M + log2f(Z);
}

// out[c,n] = x[c,n] + sum_m v[c,m] * 2^(S'(m,n) - e(m)).
// Block: 128c x 64n, 8 waves = 4 m-splits (ms) x 2 n-halves (nf). Grid 512,
// XCD swizzle. Pipeline: S[i], PV[i-1], loads[i+1], exp2/pack[i]. R17 body
// with raw-v_exp exp2 (saves 16 v_mul/body vs R17's __expf); NO setprio
// (R21 regression). permlane32_swap builtin; truncating pk2.
#define PIPE_BODY(qC0, qC1, vP, eC, qN0, qN1, vN, eN, qpN0, qpN1, vpN0, vpN1, epN, DO_LOAD) \
  {                                                                             \
    f32x16 sf = {};                                                             \
    sf = __builtin_amdgcn_mfma_f32_32x32x16_bf16(qC0, kB0, sf, 0, 0, 0);        \
    sf = __builtin_amdgcn_mfma_f32_32x32x16_bf16(qC1, kB1, sf, 0, 0, 0);        \
    _Pragma("unroll")                                                           \
    for (int ct = 0; ct < 4; ++ct) {                                            \
      acc[ct] = __builtin_amdgcn_mfma_f32_32x32x16_bf16(vP[ct][0], pf0, acc[ct], 0, 0, 0); \
      acc[ct] = __builtin_amdgcn_mfma_f32_32x32x16_bf16(vP[ct][1], pf1, acc[ct], 0, 0, 0); \
    }                                                                           \
    if (DO_LOAD) {                                                              \
      qN0 = ld_bf8(qpN0); qN1 = ld_bf8(qpN1);                                   \
      _Pragma("unroll")                                                         \
      for (int ct = 0; ct < 4; ++ct) {                                          \
        vN[ct][0] = ld_bf8(vpN0 + ct * 256);                                    \
        vN[ct][1] = ld_bf8(vpN1 + ct * 256);                                    \
      }                                                                         \
      _Pragma("unroll")                                                         \
      for (int g = 0; g < 4; ++g)                                               \
        eN[g] = *reinterpret_cast<const f32x4*>(epN + 8 * g);                   \
      qpN0 += 2048; qpN1 += 2048; vpN0 += 65536; vpN1 += 65536; epN += 256;     \
    }                                                                           \
    unsigned W0 = pk2(ex2(sf[0]  - eC[0][0]), ex2(sf[1]  - eC[0][1]));          \
    unsigned W1 = pk2(ex2(sf[2]  - eC[0][2]), ex2(sf[3]  - eC[0][3]));          \
    unsigned W2 = pk2(ex2(sf[4]  - eC[1][0]), ex2(sf[5]  - eC[1][1]));          \
    unsigned W3 = pk2(ex2(sf[6]  - eC[1][2]), ex2(sf[7]  - eC[1][3]));          \
    unsigned W4 = pk2(ex2(sf[8]  - eC[2][0]), ex2(sf[9]  - eC[2][1]));          \
    unsigned W5 = pk2(ex2(sf[10] - eC[2][2]), ex2(sf[11] - eC[2][3]));          \
    unsigned W6 = pk2(ex2(sf[12] - eC[3][0]), ex2(sf[13] - eC[3][1]));          \
    unsigned W7 = pk2(ex2(sf[14] - eC[3][2]), ex2(sf[15] - eC[3][3]));          \
    i32x2 s02 = __builtin_amdgcn_permlane32_swap((int)W0, (int)W2, false, false);\
    i32x2 s13 = __builtin_amdgcn_permlane32_swap((int)W1, (int)W3, false, false);\
    i32x2 s46 = __builtin_amdgcn_permlane32_swap((int)W4, (int)W6, false, false);\
    i32x2 s57 = __builtin_amdgcn_permlane32_swap((int)W5, (int)W7, false, false);\
    union { int u[4]; bf16x8 v8_; } f0, f1;                                     \
    f0.u[0] = s02[0]; f0.u[1] = s13[0]; f0.u[2] = s02[1]; f0.u[3] = s13[1];     \
    f1.u[0] = s46[0]; f1.u[1] = s57[0]; f1.u[2] = s46[1]; f1.u[3] = s57[1];     \
    pf0 = f0.v8_; pf1 = f1.v8_;                                                 \
  }

__global__ __launch_bounds__(512) void pv_attn(
    const __hip_bfloat16* __restrict__ q8, const __hip_bfloat16* __restrict__ k8,
    const __hip_bfloat16* __restrict__ v8, const float* __restrict__ rowE,
    const float* __restrict__ x, float* __restrict__ out)
{
    const int bid = blockIdx.x;
    const int xcd = bid & 7, slot = bid >> 3;
    const int b = xcd >> 1, c0 = (xcd & 1) * 128, n0 = slot * 64;
    const int tid = threadIdx.x, lane = tid & 63, w = tid >> 6;
    const int ms = w >> 1, nf = w & 1;
    const int h = lane >> 5, l31 = lane & 31;
    const __hip_bfloat16* q8b = q8 + (size_t)b * N_ * CB_;
    const __hip_bfloat16* k8b = k8 + (size_t)b * N_ * CB_;
    const __hip_bfloat16* v8b = v8 + (size_t)b * (N_ / 8) * C_ * 8;

    // K B-frags for this wave's n-slice (loop-invariant)
    const int nrow = n0 + nf * 32 + l31;
    bf16x8 kB0 = ld_bf8(k8b + ((size_t)h * N_ + nrow) * 8);
    bf16x8 kB1 = ld_bf8(k8b + ((size_t)(2 + h) * N_ + nrow) * 8);

    // ping-pong pointers (A: even 128-m windows, B: odd)
    const __hip_bfloat16* qpA0 = q8b + ((size_t)h * N_ + ms * 32 + l31) * 8;
    const __hip_bfloat16* qpA1 = q8b + ((size_t)(2 + h) * N_ + ms * 32 + l31) * 8;
    const __hip_bfloat16* qpB0 = qpA0 + 128 * 8;
    const __hip_bfloat16* qpB1 = qpA1 + 128 * 8;
    const __hip_bfloat16* vpA0 = v8b + ((size_t)(ms * 4 + h) * C_ + c0 + l31) * 8;
    const __hip_bfloat16* vpA1 = v8b + ((size_t)(ms * 4 + 2 + h) * C_ + c0 + l31) * 8;
    const __hip_bfloat16* vpB0 = vpA0 + (size_t)16 * C_ * 8;
    const __hip_bfloat16* vpB1 = vpA1 + (size_t)16 * C_ * 8;
    const float* epA = rowE + (size_t)b * N_ + 4 * h + ms * 32;
    const float* epB = epA + 128;

    f32x16 acc[4] = {};
    bf16x8 qA0, qA1, qB0, qB1;
    bf16x8 vA[4][2], vB[4][2];
    f32x4 eA[4], eB[4];
    bf16x8 pf0, pf1;

    // prologue: load set A (window 0)
    qA0 = ld_bf8(qpA0); qA1 = ld_bf8(qpA1);
#pragma unroll
    for (int ct = 0; ct < 4; ++ct) {
        vA[ct][0] = ld_bf8(vpA0 + ct * 256);
        vA[ct][1] = ld_bf8(vpA1 + ct * 256);
    }
#pragma unroll
    for (int g = 0; g < 4; ++g)
        eA[g] = *reinterpret_cast<const f32x4*>(epA + 8 * g);
    qpA0 += 2048; qpA1 += 2048; vpA0 += 65536; vpA1 += 65536; epA += 256;

    // S[0] + exp2/pack -> pf (no PV yet)
    {
        f32x16 sf = {};
        sf = __builtin_amdgcn_mfma_f32_32x32x16_bf16(qA0, kB0, sf, 0, 0, 0);
        sf = __builtin_amdgcn_mfma_f32_32x32x16_bf16(qA1, kB1, sf, 0, 0, 0);
        unsigned W0 = pk2(ex2(sf[0]  - eA[0][0]), ex2(sf[1]  - eA[0][1]));
        unsigned W1 = pk2(ex2(sf[2]  - eA[0][2]), ex2(sf[3]  - eA[0][3]));
        unsigned W2 = pk2(ex2(sf[4]  - eA[1][0]), ex2(sf[5]  - eA[1][1]));
        unsigned W3 = pk2(ex2(sf[6]  - eA[1][2]), ex2(sf[7]  - eA[1][3]));
        unsigned W4 = pk2(ex2(sf[8]  - eA[2][0]), ex2(sf[9]  - eA[2][1]));
        unsigned W5 = pk2(ex2(sf[10] - eA[2][2]), ex2(sf[11] - eA[2][3]));
        unsigned W6 = pk2(ex2(sf[12] - eA[3][0]), ex2(sf[13] - eA[3][1]));
        unsigned W7 = pk2(ex2(sf[14] - eA[3][2]), ex2(sf[15] - eA[3][3]));
        i32x2 s02 = __builtin_amdgcn_permlane32_swap((int)W0, (int)W2, false, false);
        i32x2 s13 = __builtin_amdgcn_permlane32_swap((int)W1, (int)W3, false, false);
        i32x2 s46 = __builtin_amdgcn_permlane32_swap((int)W4, (int)W6, false, false);
        i32x2 s57 = __builtin_amdgcn_permlane32_swap((int)W5, (int)W7, false, false);
        union { int u[4]; bf16x8 v8_; } f0, f1;
        f0.u[0] = s02[0]; f0.u[1] = s13[0]; f0.u[2] = s02[1]; f0.u[3] = s13[1];
        f1.u[0] = s46[0]; f1.u[1] = s57[0]; f1.u[2] = s46[1]; f1.u[3] = s57[1];
        pf0 = f0.v8_; pf1 = f1.v8_;
    }
    // load set B (window 1)
    qB0 = ld_bf8(qpB0); qB1 = ld_bf8(qpB1);
#pragma unroll
    for (int ct = 0; ct < 4; ++ct) {
        vB[ct][0] = ld_bf8(vpB0 + ct * 256);
        vB[ct][1] = ld_bf8(vpB1 + ct * 256);
    }
#pragma unroll
    for (int g = 0; g < 4; ++g)
        eB[g] = *reinterpret_cast<const f32x4*>(epB + 8 * g);
    qpB0 += 2048; qpB1 += 2048; vpB0 += 65536; vpB1 += 65536; epB += 256;

    // pipelined bodies i=1..31 — rolled
#pragma unroll 1
    for (int it = 0; it < 15; ++it) {
        PIPE_BODY(qB0, qB1, vA, eB, qA0, qA1, vA, eA, qpA0, qpA1, vpA0, vpA1, epA, true)
        PIPE_BODY(qA0, qA1, vB, eA, qB0, qB1, vB, eB, qpB0, qpB1, vpB0, vpB1, epB, true)
    }
    PIPE_BODY(qB0, qB1, vA, eB, qA0, qA1, vA, eA, qpA0, qpA1, vpA0, vpA1, epA, false)
    // epilogue: PV[31] from set B
#pragma unroll
    for (int ct = 0; ct < 4; ++ct) {
        acc[ct] = __builtin_amdgcn_mfma_f32_32x32x16_bf16(vB[ct][0], pf0, acc[ct], 0, 0, 0);
        acc[ct] = __builtin_amdgcn_mfma_f32_32x32x16_bf16(vB[ct][1], pf1, acc[ct], 0, 0, 0);
    }

    // 4-phase ms-reduction through LDS (nf pair writes disjoint columns)
    __shared__ __attribute__((aligned(16))) float R[128][68];
#pragma unroll 1
    for (int p = 3; p >= 0; --p) {
        if (ms == p) {
#pragma unroll
            for (int i = 0; i < 16; ++i) {
                const int cl = (i & 3) + 8 * (i >> 2) + 4 * h;
                const int nn = nf * 32 + l31;
#pragma unroll
                for (int ct = 0; ct < 4; ++ct) {
                    if (p == 3) R[ct * 32 + cl][nn] = acc[ct][i];
                    else        R[ct * 32 + cl][nn] += acc[ct][i];
                }
            }
        }
        __syncthreads();
    }
    // epilogue: out = R + x (128 rows x 64 cols, 16 floats/thread)
    const int cr = tid >> 2, n16 = (tid & 3) * 16;
#pragma unroll
    for (int j = 0; j < 4; ++j) {
        f32x4 rv = *reinterpret_cast<const f32x4*>(&R[cr][n16 + 4 * j]);
        const size_t gi = ((size_t)b * C_ + c0 + cr) * N_ + n0 + n16 + 4 * j;
        f32x4 xv = *reinterpret_cast<const f32x4*>(x + gi);
        *reinterpret_cast<f32x4*>(out + gi) = rv + xv;
    }
}

extern "C" void kernel_launch(void* const* d_in, const int* in_sizes, int n_in,
                              void* d_out, int out_size, void* d_ws, size_t ws_size,
                              hipStream_t stream)
{
    const float* x  = (const float*)d_in[0];
    const float* Wq = (const float*)d_in[1];
    const float* bq = (const float*)d_in[2];
    const float* Wk = (const float*)d_in[3];
    const float* bk = (const float*)d_in[4];
    const float* Wv = (const float*)d_in[5];
    const float* bv = (const float*)d_in[6];
    float* out = (float*)d_out;

    char* ws = (char*)d_ws;
    __hip_bfloat16* Wc   = (__hip_bfloat16*)(ws);
    __hip_bfloat16* q8   = (__hip_bfloat16*)(ws + 0x040000);
    __hip_bfloat16* k8   = (__hip_bfloat16*)(ws + 0x140000);
    float*          rowE = (float*)(ws + 0x240000);
    float*          pM   = (float*)(ws + 0x250000);
    float*          pZ   = (float*)(ws + 0x290000);
    __hip_bfloat16* v8   = (__hip_bfloat16*)(ws + 0x400000);

    wconv<<<80, 256, 0, stream>>>(Wq, Wk, Wv, Wc);
    qkv_gemm<<<dim3(N_ / 64, B_), 256, 0, stream>>>(x, Wc, bq, bk, bv, q8, k8, v8);
    row_stats_part<<<dim3(N_ / 64, 4, B_), 256, 0, stream>>>(q8, k8, pM, pZ);
    stats_combine<<<B_ * N_ / 256, 256, 0, stream>>>(pM, pZ, rowE);
    pv_attn<<<512, 512, 0, stream>>>(q8, k8, v8, rowE, x, out);
}